// Round 9
// baseline (238.046 us; speedup 1.0000x reference)
//
#include <hip/hip_runtime.h>
#include <hip/hip_bf16.h>

// Swin3D MHSA: B=256 windows, N=392 tokens, DIM=128, H=4 heads, dh=32.
// R9: attention jt-loop fuses both rb tiles (shared K/V LDS reads, 2x ILP),
//     bias table precomputed as f32 (no per-use lshl), bf16 packing via
//     __float2bfloat16 casts so the compiler can emit v_cvt_pk_bf16_f32.
//     PV stays register-resident via mfma_f32_16x16x16bf16_1k (R8).

typedef __attribute__((ext_vector_type(8))) short bf16x8;
typedef __attribute__((ext_vector_type(4))) float f32x4;
typedef __attribute__((ext_vector_type(4))) short s16x4;
typedef __attribute__((ext_vector_type(2))) unsigned int u32x2;

#define NTOK 392
#define NN (NTOK * NTOK)   // 153664
#define TABLE 2535         // 15*13*13
#define SCALE 0.17677669529663689f  // 1/sqrt(32)

__device__ __forceinline__ unsigned short f2bf(float f) {  // non-hot paths
  union { float f; unsigned u; } v; v.f = f;
  unsigned r = v.u + 0x7FFFu + ((v.u >> 16) & 1u);
  return (unsigned short)(r >> 16);
}
__device__ __forceinline__ unsigned short f2bf_rn(float f) {  // hot paths: let
  union { __hip_bfloat16 h; unsigned short u; } v;            // compiler fuse
  v.h = __float2bfloat16(f);                                  // into cvt_pk
  return v.u;
}
__device__ __forceinline__ unsigned pk2(float lo, float hi) {
  return (unsigned)f2bf_rn(lo) | ((unsigned)f2bf_rn(hi) << 16);
}

// ---------------- K0: one-time weight conversion f32 -> bf16 ----------------
__global__ __launch_bounds__(256) void wcvt_kernel(
    const float* __restrict__ Wqkv, const float* __restrict__ Wp,
    unsigned short* __restrict__ wqbf, unsigned short* __restrict__ wpbf) {
  int g = blockIdx.x * 256 + threadIdx.x;  // 16384 threads x 4 elems
  const float* src; unsigned short* dst; int off;
  if (g < 12288) { src = Wqkv; dst = wqbf; off = g * 4; }
  else           { src = Wp;   dst = wpbf; off = (g - 12288) * 4; }
  f32x4 v = *(const f32x4*)(src + off);
  s16x4 o;
  o[0] = (short)f2bf(v[0]); o[1] = (short)f2bf(v[1]);
  o[2] = (short)f2bf(v[2]); o[3] = (short)f2bf(v[3]);
  *(s16x4*)(dst + off) = o;
}

// ---------------- K1: bias in MFMA lane layout, f32 ----------------
__global__ __launch_bounds__(256) void biaspre_kernel(
    const float* __restrict__ rpb, const int* __restrict__ relidx,
    float* __restrict__ biaspre) {
  int g = blockIdx.x * 256 + threadIdx.x;  // 4*25*25*256 = 640000
  if (g >= 640000) return;
  int r = g & 3, lane = (g >> 2) & 63;
  int t = g >> 8;
  int jt = t % 25; int t2 = t / 25;
  int rb = t2 % 25; int h = t2 / 25;
  int q = rb * 16 + (lane & 15); if (q > 391) q = 391;
  int k = jt * 16 + (lane >> 4) * 4 + r; if (k > 391) k = 391;
  int f = q * (NTOK * 4) + k * 4 + h;   // raw (n,n,H) reshape quirk
  int hs = f / NN; int p = f - hs * NN;
  biaspre[g] = rpb[hs * TABLE + relidx[p]];
}

// ---------------- K2: MEGA — fused QKV + attention ----------------
// 1 block per window, 1024 threads = 16 waves; wave w owns m-tiles {w, w+16}.
__global__ __launch_bounds__(1024, 4) void mega_kernel(
    const float* __restrict__ hidden, const unsigned short* __restrict__ wqbf,
    const float* __restrict__ bqkv, const float* __restrict__ biaspre,
    unsigned short* __restrict__ ctxbuf) {
  __shared__ unsigned short Ksh[400][40];     // 32000 B
  __shared__ unsigned short Vtsh[32][424];    // 27136 B
  __shared__ unsigned short WB[16][16][40];   // 20480 B per-wave Q-transpose
                                              // total 79616 B

  const int tid = threadIdx.x;                // 0..1023
  const int w = tid >> 6, lane = tid & 63;
  const int l15 = lane & 15, lhi = lane >> 4;
  const int b = blockIdx.x;

  // zero pads once: Ksh rows 392..399 (all 40 cols); Vtsh cols 392..423 x 32 rows
  if (tid < 512) { int r = tid >> 6, c = tid & 63; if (c < 40) Ksh[392 + r][c] = 0; }
  Vtsh[tid >> 5][392 + (tid & 31)] = 0;

  const float* hwin = hidden + (size_t)b * NTOK * 128;

  // ---- A fragments: loaded + converted ONCE (i=1 clamped for w>=9) ----
  const int mtc[2] = {w, (w + 16 < 25) ? (w + 16) : 24};
  const bool has1 = (w + 16 < 25);
  bf16x8 afr[2][4];
#pragma unroll
  for (int i = 0; i < 2; ++i) {
    int arow = mtc[i] * 16 + l15; if (arow > 391) arow = 391;
#pragma unroll
    for (int kk = 0; kk < 4; ++kk) {
      const float* ap = hwin + (size_t)arow * 128 + kk * 32 + lhi * 8;
      f32x4 lo = *(const f32x4*)ap;
      f32x4 hi = *(const f32x4*)(ap + 4);
      bf16x8 a;
      a[0] = (short)f2bf_rn(lo[0]); a[1] = (short)f2bf_rn(lo[1]);
      a[2] = (short)f2bf_rn(lo[2]); a[3] = (short)f2bf_rn(lo[3]);
      a[4] = (short)f2bf_rn(hi[0]); a[5] = (short)f2bf_rn(hi[1]);
      a[6] = (short)f2bf_rn(hi[2]); a[7] = (short)f2bf_rn(hi[3]);
      afr[i][kk] = a;
    }
  }

  for (int h = 0; h < 4; ++h) {
    __syncthreads();  // h=0: covers pad init; h>0: prev attn done reading LDS

    float bq[2], bk[2], bv[2];
#pragma unroll
    for (int jt = 0; jt < 2; ++jt) {
      int d = h * 32 + jt * 16 + l15;
      bq[jt] = bqkv[d]; bk[jt] = bqkv[128 + d]; bv[jt] = bqkv[256 + d];
    }

    bf16x8 qreg[2];
#pragma unroll
    for (int ss = 0; ss < 3; ++ss) {
      // W fragments loaded once, shared by both m-tiles
      f32x4 ac[2][2];
      ac[0][0] = 0.0f; ac[0][1] = 0.0f; ac[1][0] = 0.0f; ac[1][1] = 0.0f;
#pragma unroll
      for (int kk = 0; kk < 4; ++kk) {
        const unsigned short* wp0 =
            wqbf + ((size_t)(ss * 128 + h * 32 + l15)) * 128 + kk * 32 + lhi * 8;
        bf16x8 wf0 = *(const bf16x8*)wp0;
        bf16x8 wf1 = *(const bf16x8*)(wp0 + 16 * 128);
        ac[0][0] = __builtin_amdgcn_mfma_f32_16x16x32_bf16(afr[0][kk], wf0, ac[0][0], 0, 0, 0);
        ac[0][1] = __builtin_amdgcn_mfma_f32_16x16x32_bf16(afr[0][kk], wf1, ac[0][1], 0, 0, 0);
        ac[1][0] = __builtin_amdgcn_mfma_f32_16x16x32_bf16(afr[1][kk], wf0, ac[1][0], 0, 0, 0);
        ac[1][1] = __builtin_amdgcn_mfma_f32_16x16x32_bf16(afr[1][kk], wf1, ac[1][1], 0, 0, 0);
      }
#pragma unroll
      for (int i = 0; i < 2; ++i) {
        if (i == 1 && !has1) break;   // discard clamped duplicate
        const int tok0 = mtc[i] * 16 + lhi * 4;
        if (ss == 0) {
#pragma unroll
          for (int r = 0; r < 4; ++r) {
            WB[w][lhi * 4 + r][l15]      = f2bf_rn((ac[i][0][r] + bq[0]) * SCALE);
            WB[w][lhi * 4 + r][16 + l15] = f2bf_rn((ac[i][1][r] + bq[1]) * SCALE);
          }
          qreg[i] = *(const bf16x8*)&WB[w][l15][lhi * 8];
        } else if (ss == 1) {
#pragma unroll
          for (int r = 0; r < 4; ++r) {
            int t = tok0 + r;
            if (t < NTOK) {
              Ksh[t][l15]      = f2bf_rn(ac[i][0][r] + bk[0]);
              Ksh[t][16 + l15] = f2bf_rn(ac[i][1][r] + bk[1]);
            }
          }
        } else {
          if (tok0 < NTOK) {
            u32x2 pv;
            pv[0] = pk2(ac[i][0][0] + bv[0], ac[i][0][1] + bv[0]);
            pv[1] = pk2(ac[i][0][2] + bv[0], ac[i][0][3] + bv[0]);
            *(u32x2*)&Vtsh[l15][tok0] = pv;
            pv[0] = pk2(ac[i][1][0] + bv[1], ac[i][1][1] + bv[1]);
            pv[1] = pk2(ac[i][1][2] + bv[1], ac[i][1][3] + bv[1]);
            *(u32x2*)&Vtsh[16 + l15][tok0] = pv;
          }
        }
      }
    }
    __syncthreads();

    // ---- attention for head h: BOTH rb tiles in one jt loop ----
    const int rb_a = mtc[0], rb_b = mtc[1];
    const float* ba = biaspre + ((size_t)(h * 25 + rb_a)) * 25 * 256 + lane * 4;
    const float* bb = biaspre + ((size_t)(h * 25 + rb_b)) * 25 * 256 + lane * 4;
    bf16x8 qfa = qreg[0], qfb = qreg[1];

    f32x4 o0a = 0.0f, o1a = 0.0f, o0b = 0.0f, o1b = 0.0f;
    float ssa = 0.f, ssb = 0.f;

#pragma unroll
    for (int jt = 0; jt < 25; ++jt) {
      bf16x8 kf = *(const bf16x8*)&Ksh[jt * 16 + l15][lhi * 8];
      s16x4 vf0 = *(const s16x4*)&Vtsh[l15][jt * 16 + lhi * 4];
      s16x4 vf1 = *(const s16x4*)&Vtsh[16 + l15][jt * 16 + lhi * 4];

      f32x4 sa = __builtin_amdgcn_mfma_f32_16x16x32_bf16(kf, qfa, (f32x4)0.f, 0, 0, 0);
      f32x4 bva = *(const f32x4*)(ba + jt * 256);
      float ea0 = __expf(sa[0] + bva[0]);
      float ea1 = __expf(sa[1] + bva[1]);
      float ea2 = __expf(sa[2] + bva[2]);
      float ea3 = __expf(sa[3] + bva[3]);
      if (jt == 24 && lhi >= 2) { ea0 = 0.f; ea1 = 0.f; ea2 = 0.f; ea3 = 0.f; }
      ssa += (ea0 + ea1) + (ea2 + ea3);
      s16x4 pa;
      pa[0] = (short)f2bf_rn(ea0); pa[1] = (short)f2bf_rn(ea1);
      pa[2] = (short)f2bf_rn(ea2); pa[3] = (short)f2bf_rn(ea3);
      o0a = __builtin_amdgcn_mfma_f32_16x16x16bf16_1k(pa, vf0, o0a, 0, 0, 0);
      o1a = __builtin_amdgcn_mfma_f32_16x16x16bf16_1k(pa, vf1, o1a, 0, 0, 0);

      if (has1) {
        f32x4 sb = __builtin_amdgcn_mfma_f32_16x16x32_bf16(kf, qfb, (f32x4)0.f, 0, 0, 0);
        f32x4 bvb = *(const f32x4*)(bb + jt * 256);
        float eb0 = __expf(sb[0] + bvb[0]);
        float eb1 = __expf(sb[1] + bvb[1]);
        float eb2 = __expf(sb[2] + bvb[2]);
        float eb3 = __expf(sb[3] + bvb[3]);
        if (jt == 24 && lhi >= 2) { eb0 = 0.f; eb1 = 0.f; eb2 = 0.f; eb3 = 0.f; }
        ssb += (eb0 + eb1) + (eb2 + eb3);
        s16x4 pb;
        pb[0] = (short)f2bf_rn(eb0); pb[1] = (short)f2bf_rn(eb1);
        pb[2] = (short)f2bf_rn(eb2); pb[3] = (short)f2bf_rn(eb3);
        o0b = __builtin_amdgcn_mfma_f32_16x16x16bf16_1k(pb, vf0, o0b, 0, 0, 0);
        o1b = __builtin_amdgcn_mfma_f32_16x16x16bf16_1k(pb, vf1, o1b, 0, 0, 0);
      }
    }

    // normalize + store both tiles
#pragma unroll
    for (int i = 0; i < 2; ++i) {
      if (i == 1 && !has1) continue;
      float ssum = (i == 0) ? ssa : ssb;
      f32x4 o0 = (i == 0) ? o0a : o0b;
      f32x4 o1 = (i == 0) ? o1a : o1b;
      ssum += __shfl_xor(ssum, 16);
      ssum += __shfl_xor(ssum, 32);
      float rtot = 1.f / ssum;
      float rr[4];
#pragma unroll
      for (int r = 0; r < 4; ++r) rr[r] = __shfl(rtot, lhi * 4 + r);
#pragma unroll
      for (int r = 0; r < 4; ++r) {
        int row = mtc[i] * 16 + lhi * 4 + r;
        if (row < NTOK) {
          unsigned short* crow = ctxbuf + ((size_t)(b * NTOK) + row) * 128 + h * 32;
          crow[l15] = f2bf_rn(o0[r] * rr[r]);
          crow[16 + l15] = f2bf_rn(o1[r] * rr[r]);
        }
      }
    }
  }
}

// ---------------- K3: output projection — streaming, nt stores -------------
__global__ __launch_bounds__(256, 4) void proj_kernel(
    const unsigned short* __restrict__ ctxbuf, const unsigned short* __restrict__ wpbf,
    const float* __restrict__ bp, float* __restrict__ out) {
  const int tid = threadIdx.x;
  const int w = tid >> 6, lane = tid & 63, l15 = lane & 15, lhi = lane >> 4;
  const int trow = blockIdx.x * 64 + w * 16;

  bf16x8 af[4];
#pragma unroll
  for (int kk = 0; kk < 4; ++kk)
    af[kk] = *(const bf16x8*)(
        ctxbuf + ((size_t)(trow + l15)) * 128 + kk * 32 + lhi * 8);

  f32x4 acc[8];
#pragma unroll
  for (int jt = 0; jt < 8; ++jt) acc[jt] = 0.0f;
#pragma unroll
  for (int kk = 0; kk < 4; ++kk) {
#pragma unroll
    for (int jt = 0; jt < 8; ++jt) {
      bf16x8 wf = *(const bf16x8*)(
          wpbf + ((size_t)(jt * 16 + l15)) * 128 + kk * 32 + lhi * 8);
      acc[jt] = __builtin_amdgcn_mfma_f32_16x16x32_bf16(af[kk], wf, acc[jt], 0, 0, 0);
    }
  }
#pragma unroll
  for (int jt = 0; jt < 8; ++jt) {
    int colL = jt * 16 + l15;
    float bias = bp[colL];
#pragma unroll
    for (int r = 0; r < 4; ++r) {
      int t = trow + lhi * 4 + r;
      __builtin_nontemporal_store(acc[jt][r] + bias, &out[(size_t)t * 128 + colL]);
    }
  }
}

// ---------------- launch ----------------
extern "C" void kernel_launch(void* const* d_in, const int* in_sizes, int n_in,
                              void* d_out, int out_size, void* d_ws, size_t ws_size,
                              hipStream_t stream) {
  const float* hidden = (const float*)d_in[0];
  const float* Wqkv = (const float*)d_in[1];
  const float* bqkv = (const float*)d_in[2];
  const float* Wp = (const float*)d_in[3];
  const float* bp = (const float*)d_in[4];
  const float* rpb = (const float*)d_in[5];
  const int* relidx = (const int*)d_in[6];

  // ws: ctx (12,845,056 bf16) | biaspre (640,000 f32) | wq_bf | wp_bf
  unsigned short* ctxbuf = (unsigned short*)d_ws;
  float* biaspre = (float*)(ctxbuf + 12845056);
  unsigned short* wqbf = (unsigned short*)(biaspre + 640000);
  unsigned short* wpbf = wqbf + 49152;

  wcvt_kernel<<<64, 256, 0, stream>>>(Wqkv, Wp, wqbf, wpbf);
  biaspre_kernel<<<2500, 256, 0, stream>>>(rpb, relidx, biaspre);
  mega_kernel<<<256, 1024, 0, stream>>>(hidden, wqbf, bqkv, biaspre, ctxbuf);
  proj_kernel<<<1568, 256, 0, stream>>>(ctxbuf, wpbf, bp, (float*)d_out);
}

// Round 10
// 218.078 us; speedup vs baseline: 1.0916x; 1.0916x over previous
//
#include <hip/hip_runtime.h>
#include <hip/hip_bf16.h>

// Swin3D MHSA: B=256 windows, N=392 tokens, DIM=128, H=4 heads, dh=32.
// R10: mega split into 2 blocks/window x 2 heads each (512 thr, 8 waves):
//      - LDS 69.4 KB -> 2 independent blocks/CU (barriers sync 8 waves only;
//        cross-block phase overlap keeps SIMDs fed)
//      - R8-style un-fused per-rb attn chains (bounded live set, no spill),
//        #pragma unroll 5 on jt loop, f32 bias table
//      PV register-resident via mfma_f32_16x16x16bf16_1k.

typedef __attribute__((ext_vector_type(8))) short bf16x8;
typedef __attribute__((ext_vector_type(4))) float f32x4;
typedef __attribute__((ext_vector_type(4))) short s16x4;
typedef __attribute__((ext_vector_type(2))) unsigned int u32x2;

#define NTOK 392
#define NN (NTOK * NTOK)   // 153664
#define TABLE 2535         // 15*13*13
#define SCALE 0.17677669529663689f  // 1/sqrt(32)

__device__ __forceinline__ unsigned short f2bf(float f) {  // non-hot paths
  union { float f; unsigned u; } v; v.f = f;
  unsigned r = v.u + 0x7FFFu + ((v.u >> 16) & 1u);
  return (unsigned short)(r >> 16);
}
__device__ __forceinline__ unsigned short f2bf_rn(float f) {  // hot: compiler
  union { __hip_bfloat16 h; unsigned short u; } v;            // fuses to cvt_pk
  v.h = __float2bfloat16(f);
  return v.u;
}
__device__ __forceinline__ unsigned pk2(float lo, float hi) {
  return (unsigned)f2bf_rn(lo) | ((unsigned)f2bf_rn(hi) << 16);
}

// ---------------- K0: one-time weight conversion f32 -> bf16 ----------------
__global__ __launch_bounds__(256) void wcvt_kernel(
    const float* __restrict__ Wqkv, const float* __restrict__ Wp,
    unsigned short* __restrict__ wqbf, unsigned short* __restrict__ wpbf) {
  int g = blockIdx.x * 256 + threadIdx.x;  // 16384 threads x 4 elems
  const float* src; unsigned short* dst; int off;
  if (g < 12288) { src = Wqkv; dst = wqbf; off = g * 4; }
  else           { src = Wp;   dst = wpbf; off = (g - 12288) * 4; }
  f32x4 v = *(const f32x4*)(src + off);
  s16x4 o;
  o[0] = (short)f2bf(v[0]); o[1] = (short)f2bf(v[1]);
  o[2] = (short)f2bf(v[2]); o[3] = (short)f2bf(v[3]);
  *(s16x4*)(dst + off) = o;
}

// ---------------- K1: bias in MFMA lane layout, f32 ----------------
__global__ __launch_bounds__(256) void biaspre_kernel(
    const float* __restrict__ rpb, const int* __restrict__ relidx,
    float* __restrict__ biaspre) {
  int g = blockIdx.x * 256 + threadIdx.x;  // 4*25*25*256 = 640000
  if (g >= 640000) return;
  int r = g & 3, lane = (g >> 2) & 63;
  int t = g >> 8;
  int jt = t % 25; int t2 = t / 25;
  int rb = t2 % 25; int h = t2 / 25;
  int q = rb * 16 + (lane & 15); if (q > 391) q = 391;
  int k = jt * 16 + (lane >> 4) * 4 + r; if (k > 391) k = 391;
  int f = q * (NTOK * 4) + k * 4 + h;   // raw (n,n,H) reshape quirk
  int hs = f / NN; int p = f - hs * NN;
  biaspre[g] = rpb[hs * TABLE + relidx[p]];
}

// ---------------- K2: MEGA — fused QKV + attention ----------------
// grid (256 windows, 2 head-pairs); 512 threads = 8 waves.
// Block (b, hp) computes heads {2hp, 2hp+1} of window b.
__global__ __launch_bounds__(512, 4) void mega_kernel(
    const float* __restrict__ hidden, const unsigned short* __restrict__ wqbf,
    const float* __restrict__ bqkv, const float* __restrict__ biaspre,
    unsigned short* __restrict__ ctxbuf) {
  __shared__ unsigned short Ksh[400][40];     // 32000 B
  __shared__ unsigned short Vtsh[32][424];    // 27136 B
  __shared__ unsigned short WB[8][16][40];    // 10240 B  (total 69376 B)

  const int tid = threadIdx.x;                // 0..511
  const int w = tid >> 6, lane = tid & 63;
  const int l15 = lane & 15, lhi = lane >> 4;
  const int b = blockIdx.x;
  const int h0 = blockIdx.y * 2;

  // zero pads once: Ksh rows 392..399 (cols 0..39); Vtsh cols 392..423, 32 rows
  { int r = tid >> 6, c = tid & 63; if (c < 40) Ksh[392 + r][c] = 0; }
  { int row = tid >> 4, col = tid & 15;
    Vtsh[row][392 + col] = 0; Vtsh[row][408 + col] = 0; }

  const float* hwin = hidden + (size_t)b * NTOK * 128;

  for (int hh = 0; hh < 2; ++hh) {
    const int h = h0 + hh;
    __syncthreads();  // hh=0: covers pad init; hh=1: prev attn done reading LDS

    const float bq0 = bqkv[h * 32 + l15],       bq1 = bqkv[h * 32 + 16 + l15];
    const float bk0 = bqkv[128 + h * 32 + l15], bk1 = bqkv[128 + h * 32 + 16 + l15];
    const float bv0 = bqkv[256 + h * 32 + l15], bv1 = bqkv[256 + h * 32 + 16 + l15];

    // ---- QKV phase: wave w owns m-tiles {w, w+8, w+16, w+24<25} ----
    bf16x8 qreg[4];
#pragma unroll
    for (int t = 0; t < 4; ++t) {
      const int mt = w + t * 8;
      if (mt < 25) {
        int arow = mt * 16 + l15; if (arow > 391) arow = 391;
        bf16x8 af[4];
#pragma unroll
        for (int kk = 0; kk < 4; ++kk) {
          const float* ap = hwin + (size_t)arow * 128 + kk * 32 + lhi * 8;
          f32x4 lo = *(const f32x4*)ap;
          f32x4 hi = *(const f32x4*)(ap + 4);
          bf16x8 a;
          a[0] = (short)f2bf_rn(lo[0]); a[1] = (short)f2bf_rn(lo[1]);
          a[2] = (short)f2bf_rn(lo[2]); a[3] = (short)f2bf_rn(lo[3]);
          a[4] = (short)f2bf_rn(hi[0]); a[5] = (short)f2bf_rn(hi[1]);
          a[6] = (short)f2bf_rn(hi[2]); a[7] = (short)f2bf_rn(hi[3]);
          af[kk] = a;
        }
        const int tok0 = mt * 16 + lhi * 4;
#pragma unroll
        for (int ss = 0; ss < 3; ++ss) {
          f32x4 a0 = 0.0f, a1 = 0.0f;
#pragma unroll
          for (int kk = 0; kk < 4; ++kk) {
            const unsigned short* wp0 =
                wqbf + ((size_t)(ss * 128 + h * 32 + l15)) * 128 + kk * 32 + lhi * 8;
            bf16x8 wf0 = *(const bf16x8*)wp0;
            bf16x8 wf1 = *(const bf16x8*)(wp0 + 16 * 128);
            a0 = __builtin_amdgcn_mfma_f32_16x16x32_bf16(af[kk], wf0, a0, 0, 0, 0);
            a1 = __builtin_amdgcn_mfma_f32_16x16x32_bf16(af[kk], wf1, a1, 0, 0, 0);
          }
          if (ss == 0) {
#pragma unroll
            for (int r = 0; r < 4; ++r) {
              WB[w][lhi * 4 + r][l15]      = f2bf_rn((a0[r] + bq0) * SCALE);
              WB[w][lhi * 4 + r][16 + l15] = f2bf_rn((a1[r] + bq1) * SCALE);
            }
            qreg[t] = *(const bf16x8*)&WB[w][l15][lhi * 8];
          } else if (ss == 1) {
#pragma unroll
            for (int r = 0; r < 4; ++r) {
              int tk = tok0 + r;
              if (tk < NTOK) {
                Ksh[tk][l15]      = f2bf_rn(a0[r] + bk0);
                Ksh[tk][16 + l15] = f2bf_rn(a1[r] + bk1);
              }
            }
          } else {
            if (tok0 < NTOK) {
              u32x2 pv;
              pv[0] = pk2(a0[0] + bv0, a0[1] + bv0);
              pv[1] = pk2(a0[2] + bv0, a0[3] + bv0);
              *(u32x2*)&Vtsh[l15][tok0] = pv;
              pv[0] = pk2(a1[0] + bv1, a1[1] + bv1);
              pv[1] = pk2(a1[2] + bv1, a1[3] + bv1);
              *(u32x2*)&Vtsh[16 + l15][tok0] = pv;
            }
          }
        }
      }
    }
    __syncthreads();

    // ---- attention phase: wave w owns rb tiles {w, w+8, w+16, w+24<25} ----
    const float* biasH = biaspre + (size_t)h * 25 * 25 * 256 + lane * 4;

#pragma unroll
    for (int t = 0; t < 4; ++t) {
      const int rb = w + t * 8;
      if (rb >= 25) continue;              // wave-uniform
      bf16x8 qf = qreg[t];
      const float* bp = biasH + (size_t)rb * 25 * 256;

      f32x4 o0 = 0.0f, o1 = 0.0f;
      float ss = 0.f;

#pragma unroll 5
      for (int jt = 0; jt < 25; ++jt) {
        bf16x8 kf = *(const bf16x8*)&Ksh[jt * 16 + l15][lhi * 8];
        s16x4 vf0 = *(const s16x4*)&Vtsh[l15][jt * 16 + lhi * 4];
        s16x4 vf1 = *(const s16x4*)&Vtsh[16 + l15][jt * 16 + lhi * 4];
        f32x4 bv = *(const f32x4*)(bp + jt * 256);

        f32x4 s = __builtin_amdgcn_mfma_f32_16x16x32_bf16(kf, qf, (f32x4)0.f, 0, 0, 0);
        float e0 = __expf(s[0] + bv[0]);
        float e1 = __expf(s[1] + bv[1]);
        float e2 = __expf(s[2] + bv[2]);
        float e3 = __expf(s[3] + bv[3]);
        if (jt == 24 && lhi >= 2) { e0 = 0.f; e1 = 0.f; e2 = 0.f; e3 = 0.f; }
        ss += (e0 + e1) + (e2 + e3);
        s16x4 pa;
        pa[0] = (short)f2bf_rn(e0); pa[1] = (short)f2bf_rn(e1);
        pa[2] = (short)f2bf_rn(e2); pa[3] = (short)f2bf_rn(e3);
        o0 = __builtin_amdgcn_mfma_f32_16x16x16bf16_1k(pa, vf0, o0, 0, 0, 0);
        o1 = __builtin_amdgcn_mfma_f32_16x16x16bf16_1k(pa, vf1, o1, 0, 0, 0);
      }

      ss += __shfl_xor(ss, 16);
      ss += __shfl_xor(ss, 32);
      float rtot = 1.f / ss;
      float rr[4];
#pragma unroll
      for (int r = 0; r < 4; ++r) rr[r] = __shfl(rtot, lhi * 4 + r);

#pragma unroll
      for (int r = 0; r < 4; ++r) {
        int row = rb * 16 + lhi * 4 + r;
        if (row < NTOK) {
          unsigned short* crow = ctxbuf + ((size_t)(b * NTOK) + row) * 128 + h * 32;
          crow[l15] = f2bf_rn(o0[r] * rr[r]);
          crow[16 + l15] = f2bf_rn(o1[r] * rr[r]);
        }
      }
    }
  }
}

// ---------------- K3: output projection — streaming, nt stores -------------
__global__ __launch_bounds__(256, 4) void proj_kernel(
    const unsigned short* __restrict__ ctxbuf, const unsigned short* __restrict__ wpbf,
    const float* __restrict__ bp, float* __restrict__ out) {
  const int tid = threadIdx.x;
  const int w = tid >> 6, lane = tid & 63, l15 = lane & 15, lhi = lane >> 4;
  const int trow = blockIdx.x * 64 + w * 16;

  bf16x8 af[4];
#pragma unroll
  for (int kk = 0; kk < 4; ++kk)
    af[kk] = *(const bf16x8*)(
        ctxbuf + ((size_t)(trow + l15)) * 128 + kk * 32 + lhi * 8);

  f32x4 acc[8];
#pragma unroll
  for (int jt = 0; jt < 8; ++jt) acc[jt] = 0.0f;
#pragma unroll
  for (int kk = 0; kk < 4; ++kk) {
#pragma unroll
    for (int jt = 0; jt < 8; ++jt) {
      bf16x8 wf = *(const bf16x8*)(
          wpbf + ((size_t)(jt * 16 + l15)) * 128 + kk * 32 + lhi * 8);
      acc[jt] = __builtin_amdgcn_mfma_f32_16x16x32_bf16(af[kk], wf, acc[jt], 0, 0, 0);
    }
  }
#pragma unroll
  for (int jt = 0; jt < 8; ++jt) {
    int colL = jt * 16 + l15;
    float bias = bp[colL];
#pragma unroll
    for (int r = 0; r < 4; ++r) {
      int t = trow + lhi * 4 + r;
      __builtin_nontemporal_store(acc[jt][r] + bias, &out[(size_t)t * 128 + colL]);
    }
  }
}

// ---------------- launch ----------------
extern "C" void kernel_launch(void* const* d_in, const int* in_sizes, int n_in,
                              void* d_out, int out_size, void* d_ws, size_t ws_size,
                              hipStream_t stream) {
  const float* hidden = (const float*)d_in[0];
  const float* Wqkv = (const float*)d_in[1];
  const float* bqkv = (const float*)d_in[2];
  const float* Wp = (const float*)d_in[3];
  const float* bp = (const float*)d_in[4];
  const float* rpb = (const float*)d_in[5];
  const int* relidx = (const int*)d_in[6];

  // ws: ctx (12,845,056 bf16) | biaspre (640,000 f32) | wq_bf | wp_bf
  unsigned short* ctxbuf = (unsigned short*)d_ws;
  float* biaspre = (float*)(ctxbuf + 12845056);
  unsigned short* wqbf = (unsigned short*)(biaspre + 640000);
  unsigned short* wpbf = wqbf + 49152;

  wcvt_kernel<<<64, 256, 0, stream>>>(Wqkv, Wp, wqbf, wpbf);
  biaspre_kernel<<<2500, 256, 0, stream>>>(rpb, relidx, biaspre);
  mega_kernel<<<dim3(256, 2), 512, 0, stream>>>(hidden, wqbf, bqkv, biaspre, ctxbuf);
  proj_kernel<<<1568, 256, 0, stream>>>(ctxbuf, wpbf, bp, (float*)d_out);
}